// Round 3
// baseline (312.567 us; speedup 1.0000x reference)
//
#include <hip/hip_runtime.h>
#include <hip/hip_bf16.h>

#define SEQ   512
#define BATCH 256
#define ZD    64

typedef float vfloat2 __attribute__((ext_vector_type(2)));
typedef float vfloat4 __attribute__((ext_vector_type(4)));

__device__ __forceinline__ int lane_bcasti(int v, int i) {
  return __builtin_amdgcn_readlane(v, i);
}

// 16 group names g00..g17 (octal digit pairs, 0##n = 0..15). Group n covers
// alpha indices 4n..4n+3: pair ua##n multiplies (4n,4n+1) into acc01, pair
// ub##n multiplies (4n+2,4n+3) into acc23. This reproduces the original
// acc[i&3] 4-chain accumulation order EXACTLY (bit-identical reduce).
#define REP8(M,p)  M(p##0) M(p##1) M(p##2) M(p##3) M(p##4) M(p##5) M(p##6) M(p##7)
#define REP16(M)   REP8(M,0) REP8(M,1)

#define UDECL(n)  vfloat2 ua##n, ub##n;
#define ULOADF(n) ua##n = *(const vfloat2*)(Trp + 4*(0##n)); \
                  ub##n = *(const vfloat2*)(Trp + 4*(0##n) + 2);
#define ULOADB(n) ua##n = (vfloat2){Tcp[(4*(0##n)+0)*ZD], Tcp[(4*(0##n)+1)*ZD]}; \
                  ub##n = (vfloat2){Tcp[(4*(0##n)+2)*ZD], Tcp[(4*(0##n)+3)*ZD]};
// Uniform-address LDS read = hardware broadcast (no bank conflict). One base
// address, compile-time offsets -> ds_read_b128 offset:16n. v_pk_fma_f32 via
// __builtin_elementwise_fma on float2 halves.
#define UFMA(n)   { const vfloat4 rb = *(const vfloat4*)(albuf + 4*(0##n)); \
                    acc01 = __builtin_elementwise_fma((vfloat2){rb.x, rb.y}, ua##n, acc01); \
                    acc23 = __builtin_elementwise_fma((vfloat2){rb.z, rb.w}, ub##n, acc23); }
// Opaque register pin: stops LICM from re-sinking the T loads into the loop.
#define UPIN(p)   asm volatile("" : "+v"(ua##p##0), "+v"(ua##p##1), "+v"(ua##p##2), \
                                    "+v"(ua##p##3), "+v"(ua##p##4), "+v"(ua##p##5), \
                                    "+v"(ua##p##6), "+v"(ua##p##7), \
                                    "+v"(ub##p##0), "+v"(ub##p##1), "+v"(ub##p##2), \
                                    "+v"(ub##p##3), "+v"(ub##p##4), "+v"(ub##p##5), \
                                    "+v"(ub##p##6), "+v"(ub##p##7));
#define UPIN_ALL  UPIN(0) UPIN(1)

// One wave (64 lanes = 64 z-states) per chain; blocks 0..255 forward,
// 256..511 backward.
//
// Round 7: SGPR-broadcast elimination. Rounds 0-6 showed the per-step cost
// (~400-620 cyc vs a 256-cyc issue floor) is insensitive to memory ordering:
// the bottleneck is the 64 v_readlane -> SGPR -> v_fma chain (readlane burns
// half the VALU issue slots, and VALU-writes-SGPR -> VALU-reads-SGPR hazards
// serialize on the finite SGPR pool). New scheme: write the 64-vector being
// broadcast to a 256B LDS buffer once per step (single wave -> DS pipe is
// in-order, no barrier needed), read it back as 16 uniform-address
// ds_read_b128 (same-address = broadcast, conflict-free), and feed
// v_pk_fma_f32 (32 packed ops replace 64 scalar FMAs). VALU ops/step drop
// 128 -> ~40; the broadcast moves to the DS pipe which runs in parallel.
__global__ __launch_bounds__(64, 1) void hmm_chains(
    const int*   __restrict__ inp,    // [SEQ, BATCH]
    const float* __restrict__ T,      // [ZD, ZD] row-major
    const float* __restrict__ pi,     // [ZD]
    const float* __restrict__ emit,   // [X, ZD]
    float* __restrict__ out_alpha,    // [SEQ, BATCH, ZD] fp32
    float* __restrict__ out_beta)     // [SEQ, BATCH, ZD] fp32
{
  const int lane = threadIdx.x;
  const int blk  = blockIdx.x;
  const bool fwd = (blk < BATCH);
  const int b    = fwd ? blk : blk - BATCH;

  __shared__ alignas(16) float albuf[ZD];

  REP16(UDECL)

  if (fwd) {
    // Shifted x registers: xvn[w] lane l = x[min(64w+l+1, 511)] so the
    // in-iter prefetch index x[t+1] is a single readlane.
    int xvn[8];
    #pragma unroll
    for (int w = 0; w < 8; ++w) {
      int li = w * 64 + lane + 1;
      if (li > SEQ - 1) li = SEQ - 1;
      xvn[w] = inp[li * BATCH + b];
    }

    // alpha_t[l] = e_t[l] * sum_i alpha_{t-1}[i] * T[l][i]
    const float* Trp = T + lane * ZD;
    REP16(ULOADF)
    UPIN_ALL

    const int x0 = inp[b];                   // x[0], uniform scalar load
    float alpha = emit[x0 * ZD + lane] * pi[lane];
    float* op = out_alpha + (size_t)b * ZD + lane;

    const int x1 = lane_bcasti(xvn[0], 0);
    float e_cur = emit[x1 * ZD + lane];      // e_1
    __builtin_nontemporal_store(alpha, op);
    op += BATCH * ZD;

    #pragma unroll
    for (int w = 0; w < 8; ++w) {
      const int xnw = xvn[w];
      #pragma unroll 1                 // keep body small, inside L1I
      for (int idx = (w == 0) ? 1 : 0; idx < 64; ++idx) {
        const int   xt1  = lane_bcasti(xnw, idx);   // x[t+1] (uniform)
        const float e_pf = emit[xt1 * ZD + lane];   // used next iter
        albuf[lane] = alpha;                        // ds_write; in-order DS pipe
        vfloat2 acc01 = {0.f, 0.f}, acc23 = {0.f, 0.f};
        REP16(UFMA)                                 // 16 b128 bcast + 32 pk_fma
        alpha = e_cur * ((acc01.x + acc01.y) + (acc23.x + acc23.y));
        __builtin_nontemporal_store(alpha, op);
        op += BATCH * ZD;
        e_cur = e_pf;
      }
    }
  } else {
    // beta_t[l] = sum_j (e_{t+1}[j]*beta_{t+1}[j]) * T[j][l]
    int xv[8];
    #pragma unroll
    for (int w = 0; w < 8; ++w)
      xv[w] = inp[(w * 64 + lane) * BATCH + b];

    const float* Tcp = T + lane;
    REP16(ULOADB)
    UPIN_ALL

    float beta = 1.0f;
    float* op = out_beta + ((size_t)(SEQ - 1) * BATCH + b) * ZD + lane;
    __builtin_nontemporal_store(beta, op);
    op -= BATCH * ZD;

    const int xL = lane_bcasti(xv[7], 63);
    float e_next = emit[xL * ZD + lane];          // e_{511}, consumed at t=510

    #pragma unroll
    for (int w = 7; w >= 0; --w) {
      const int xvw = xv[w];
      #pragma unroll 1
      for (int idx = (w == 7) ? 62 : 63; idx >= 0; --idx) {
        const int   xt   = lane_bcasti(xvw, idx); // x_t, e for next iteration
        const float e_pf = emit[xt * ZD + lane];  // used next iter
        const float g    = e_next * beta;         // broadcast source g[j]
        albuf[lane] = g;                          // ds_write
        vfloat2 acc01 = {0.f, 0.f}, acc23 = {0.f, 0.f};
        REP16(UFMA)
        beta = (acc01.x + acc01.y) + (acc23.x + acc23.y);
        __builtin_nontemporal_store(beta, op);
        op -= BATCH * ZD;
        e_next = e_pf;
      }
    }
  }
}

// posterior[t,b,z] = alpha*beta / sum_z(alpha*beta). 8 z per lane (2x vfloat4),
// 8 lanes per (t,b) row, xor-shuffle reduction within the 8-lane group.
__global__ __launch_bounds__(256) void posterior_k(
    const float* __restrict__ a,
    const float* __restrict__ bt,
    float*       __restrict__ p)
{
  const int tid = blockIdx.x * 256 + threadIdx.x;
  const size_t base = (size_t)tid * 8;

  const vfloat4 va0 = __builtin_nontemporal_load(reinterpret_cast<const vfloat4*>(a  + base));
  const vfloat4 va1 = __builtin_nontemporal_load(reinterpret_cast<const vfloat4*>(a  + base + 4));
  const vfloat4 vb0 = __builtin_nontemporal_load(reinterpret_cast<const vfloat4*>(bt + base));
  const vfloat4 vb1 = __builtin_nontemporal_load(reinterpret_cast<const vfloat4*>(bt + base + 4));

  const float p0 = va0.x * vb0.x;
  const float p1 = va0.y * vb0.y;
  const float p2 = va0.z * vb0.z;
  const float p3 = va0.w * vb0.w;
  const float p4 = va1.x * vb1.x;
  const float p5 = va1.y * vb1.y;
  const float p6 = va1.z * vb1.z;
  const float p7 = va1.w * vb1.w;

  float s = ((p0 + p1) + (p2 + p3)) + ((p4 + p5) + (p6 + p7));
  s += __shfl_xor(s, 1);
  s += __shfl_xor(s, 2);
  s += __shfl_xor(s, 4);
  const float inv = 1.0f / s;

  vfloat4 o0, o1;
  o0.x = p0 * inv; o0.y = p1 * inv; o0.z = p2 * inv; o0.w = p3 * inv;
  o1.x = p4 * inv; o1.y = p5 * inv; o1.z = p6 * inv; o1.w = p7 * inv;
  __builtin_nontemporal_store(o0, reinterpret_cast<vfloat4*>(p + base));
  __builtin_nontemporal_store(o1, reinterpret_cast<vfloat4*>(p + base + 4));
}

extern "C" void kernel_launch(void* const* d_in, const int* in_sizes, int n_in,
                              void* d_out, int out_size, void* d_ws, size_t ws_size,
                              hipStream_t stream) {
  const int*   inp  = (const int*)  d_in[0];
  const float* T    = (const float*)d_in[1];
  const float* pi   = (const float*)d_in[2];
  const float* emit = (const float*)d_in[3];

  float* out = (float*)d_out;
  const size_t N = (size_t)SEQ * BATCH * ZD;   // 8388608 per output
  float* out_alpha = out;
  float* out_beta  = out + N;
  float* out_post  = out + 2 * N;

  hipLaunchKernelGGL(hmm_chains, dim3(2 * BATCH), dim3(64), 0, stream,
                     inp, T, pi, emit, out_alpha, out_beta);

  hipLaunchKernelGGL(posterior_k, dim3((unsigned)(N / 2048)), dim3(256), 0, stream,
                     out_alpha, out_beta, out_post);
}